// Round 20
// baseline (577.626 us; speedup 1.0000x reference)
//
#include <hip/hip_runtime.h>
#include <hip/hip_bf16.h>
#include <hip/hip_fp16.h>
#include <cstdint>
#include <cstddef>

#define NB   131072   // items
#define ED   256      // e_dim
#define NQL  4        // levels
#define NEC  256      // codebook entries

typedef _Float16 f16;
typedef f16  f16x8  __attribute__((ext_vector_type(8)));
typedef float f32x4  __attribute__((ext_vector_type(4)));
typedef float f32x16 __attribute__((ext_vector_type(16)));

static constexpr float FMAXV = 3.402823466e+38f;
static constexpr float TAUH  = 0.078125f;   // rescore gate, d/2 units

static constexpr size_t OFF_REC  = (size_t)NB * ED;
static constexpr size_t OFF_LOSS = 2 * (size_t)NB * ED;
static constexpr size_t OFF_SIDX = OFF_LOSS + 1;
static constexpr size_t OFF_RIDX = OFF_SIDX + (size_t)NB * NQL;

// workspace layout (bytes)
static constexpr size_t WS_LOSS = 0;                      // 8 doubles
static constexpr size_t WS_NORM = 256;                    // 8*256 f32 (norm - 256)
static constexpr size_t WS_CBH  = 256 + 8 * 256 * 4;      // 8448; 8*256*256 f16 (1 MB)

// ---- prep: zero loss accumulators + codebook row norms (pre-shifted by -256) ----
__global__ void kPrep(const float* __restrict__ cbS, const float* __restrict__ cbR,
                      float* __restrict__ norms, double* __restrict__ lossAcc) {
  const int cbi = blockIdx.x;    // 0..7
  const int j   = threadIdx.x;   // 0..255
  if (cbi == 0 && j < 8) lossAcc[j] = 0.0;
  const float* row = (cbi < 4 ? cbS : cbR) + ((size_t)(cbi & 3) * NEC + j) * ED;
  float acc = 0.f;
  for (int k = 0; k < ED; k += 4) {
    float4 v = *(const float4*)(row + k);
    acc += v.x * v.x + v.y * v.y + v.z * v.z + v.w * v.w;
  }
  norms[cbi * NEC + j] = acc - 256.0f;   // exact shift (Sterbenz range)
}

// ---- NEGATED f16 copy of codebooks: acc = 0.5*nrm + sum(-c)*r = d/2 ----
__global__ void kConvH(const float* __restrict__ cbS, const float* __restrict__ cbR,
                       f16* __restrict__ cbH) {
  const int f   = blockIdx.x * 256 + threadIdx.x;   // 0..524287
  const int cbi = f >> 16;
  const int rem = f & 65535;
  const float v = (cbi < 4 ? cbS + ((size_t)cbi << 16) : cbR + ((size_t)(cbi - 4) << 16))[rem];
  cbH[f] = (f16)(-v);   // RTN, negated
}

// packed key helpers: low 8 mantissa bits carry the codeword index
__device__ __forceinline__ float pk(float v, int j) {
  return __uint_as_float((__float_as_uint(v) & ~255u) | (unsigned)j);
}
__device__ __forceinline__ float unpv(float k) {
  return __uint_as_float(__float_as_uint(k) & ~255u);
}
__device__ __forceinline__ void ins3(float& s0, float& s1, float& s2, float k) {
  float t0 = fmaxf(s0, k); s0 = fminf(s0, k);
  float t1 = fmaxf(s1, t0); s1 = fminf(s1, t0);
  s2 = fminf(s2, t1);
}
__device__ __forceinline__ void mrg3(float& a0, float& a1, float& a2,
                                     float b0, float b1, float b2) {
  float x  = fmaxf(a0, b0);
  float c0 = fminf(a0, b0);
  float m1 = fminf(a1, b1), M1 = fmaxf(a1, b1);
  float c1 = fminf(fminf(x, a1), b1);
  float c2 = fminf(fminf(fmaxf(x, m1), M1), fminf(a2, b2));
  a0 = c0; a1 = c1; a2 = c2;
}

// ---- main fused RVQ kernel: r13 structure with 32x32x16 MFMA ----
// Same 64x64/wave tile, same loads (8x16B per K=32 batch), same 64-VGPR
// fragment + 64-AGPR acc budget — but HALF the MFMA instructions (64 vs 128
// per wave-level), ~17% fewer matrix-pipe cycles (m119), and the 32x32 C/D
// layout (col=lane&31, row=(reg&3)+8*(reg>>2)+4*(lane>>5)) puts 32 j-keys
// in-lane per item -> fold merge = 1 xor-32 butterfly (6 shuffles vs 24).
// LDS swizzle upgraded to ^(item&15)<<4 (both sides) for 2-way reads.
__global__ __launch_bounds__(256, 2)
void kMain(const float* __restrict__ x,
           const float* __restrict__ cbS,
           const float* __restrict__ cbR,
           const f16*  __restrict__ cbH,
           const float* __restrict__ norms,
           double* __restrict__ lossAcc,
           float* __restrict__ out) {
  __shared__ __align__(16) char  RhBuf[64 * 512];      // f16 residual image (32 KB)
  __shared__ __align__(16) float keybuf[64][4][4];     // per-wave top-3 per item (4 KB)
  __shared__ float redS[4];

  const int tid   = threadIdx.x;
  const int lane  = tid & 63;
  const int w     = tid >> 6;       // wave: owns codewords [64w, 64w+64)
  const int it_o  = tid >> 2;       // owner item 0..63
  const int kq    = tid & 3;        // owner k-quarter
  const int b0    = blockIdx.x * 64;
  const int br    = blockIdx.y;     // branch (src/rec) — one 4-level chain/block
  const int l31   = lane & 31;
  const int hl    = lane >> 5;

  const float* cbf32base = br ? cbR : cbS;
  float res[64];
  float lossA = 0.f, lossB = 0.f;

  // ---- load residual = x[:, br*E .. br*E+E) slice into registers ----
  {
    const float* xp = x + (size_t)(b0 + it_o) * (2 * ED) + br * ED + kq * 64;
#pragma unroll
    for (int i = 0; i < 16; ++i) {
      float4 v = *(const float4*)(xp + 4 * i);
      res[4 * i + 0] = v.x; res[4 * i + 1] = v.y;
      res[4 * i + 2] = v.z; res[4 * i + 3] = v.w;
    }
  }

#pragma unroll 1
  for (int lev = 0; lev < NQL; ++lev) {
    const int cbi = br * 4 + lev;
    const float* nrm = norms + (size_t)cbi * NEC;
    const f16*   cbh = cbH + ((size_t)cbi << 16);
    const float* cbf32 = cbf32base + (size_t)lev * NEC * ED;

    // ---- stage res -> Rh (f16, RTN), 16B granule XOR-swizzle (item&15) ----
#pragma unroll
    for (int c = 0; c < 8; ++c) {
      f16x8 h;
#pragma unroll
      for (int u = 0; u < 8; ++u) h[u] = (f16)res[c * 8 + u];
      const int g = (kq * 8 + c) ^ (it_o & 15);
      *(f16x8*)&RhBuf[it_o * 512 + g * 16] = h;
    }
    __syncthreads();   // barrier 1: Rh ready

    // ---- acc init = 0.5*nrm at D-layout rows -> acc_final = d/2 ----
    f32x16 acc[2][2];   // [item-tile ct][j-tile jt]
#pragma unroll
    for (int jt = 0; jt < 2; ++jt) {
#pragma unroll
      for (int q = 0; q < 4; ++q) {
        float4 nv = *(const float4*)&nrm[w * 64 + jt * 32 + 8 * q + 4 * hl];
        acc[0][jt][4 * q + 0] = 0.5f * nv.x; acc[0][jt][4 * q + 1] = 0.5f * nv.y;
        acc[0][jt][4 * q + 2] = 0.5f * nv.z; acc[0][jt][4 * q + 3] = 0.5f * nv.w;
        acc[1][jt][4 * q + 0] = 0.5f * nv.x; acc[1][jt][4 * q + 1] = 0.5f * nv.y;
        acc[1][jt][4 * q + 2] = 0.5f * nv.z; acc[1][jt][4 * q + 3] = 0.5f * nv.w;
      }
    }

    // ---- GEMM: 4x 32x32 tiles/wave, 2-deep ping-pong, K=32 batches ----
    f16x8 C0[2][2], R0[2][2], C1[2][2], R1[2][2];   // [jt|ct][k-substep]
#define LOADC(Cd, bs_)                                                          \
    {                                                                           \
      _Pragma("unroll")                                                         \
      for (int jt = 0; jt < 2; ++jt)                                            \
        _Pragma("unroll")                                                       \
        for (int s = 0; s < 2; ++s)                                             \
          Cd[jt][s] = *(const f16x8*)&cbh[(size_t)(w * 64 + jt * 32 + l31) * ED \
                                          + (2 * (bs_) + s) * 16 + hl * 8];     \
    }
#define LOADR(Rd, bs_)                                                          \
    {                                                                           \
      _Pragma("unroll")                                                         \
      for (int ct = 0; ct < 2; ++ct)                                            \
        _Pragma("unroll")                                                       \
        for (int s = 0; s < 2; ++s) {                                           \
          const int item = ct * 32 + l31;                                       \
          const int g = ((2 * (bs_) + s) * 2 + hl) ^ (l31 & 15);                \
          Rd[ct][s] = *(const f16x8*)&RhBuf[item * 512 + g * 16];               \
        }                                                                       \
    }
#define MFMA8(Cb, Rs)                                                           \
    {                                                                           \
      __builtin_amdgcn_s_setprio(1);                                            \
      _Pragma("unroll")                                                         \
      for (int s = 0; s < 2; ++s)                                               \
        _Pragma("unroll")                                                       \
        for (int ct = 0; ct < 2; ++ct)                                          \
          _Pragma("unroll")                                                     \
          for (int jt = 0; jt < 2; ++jt)                                        \
            acc[ct][jt] = __builtin_amdgcn_mfma_f32_32x32x16_f16(               \
                Cb[jt][s], Rs[ct][s], acc[ct][jt], 0, 0, 0);                    \
      __builtin_amdgcn_s_setprio(0);                                            \
    }

    LOADC(C0, 0); LOADR(R0, 0);
#pragma unroll 1
    for (int bs2 = 0; bs2 < 4; ++bs2) {
      LOADC(C1, 2 * bs2 + 1); LOADR(R1, 2 * bs2 + 1);   // issue next batch first
      MFMA8(C0, R0);
      if (bs2 < 3) { LOADC(C0, 2 * bs2 + 2); LOADR(R0, 2 * bs2 + 2); }
      MFMA8(C1, R1);
    }
#undef LOADC
#undef LOADR
#undef MFMA8

    // ---- argmin fold: lane holds 32 j-keys (2 jt x 16 regs) per item-tile ----
#pragma unroll
    for (int ct = 0; ct < 2; ++ct) {
      float sa0 = FMAXV, sa1 = FMAXV, sa2 = FMAXV;
      float sb0 = FMAXV, sb1 = FMAXV, sb2 = FMAXV;
#pragma unroll
      for (int r = 0; r < 16; ++r) {
        const int rowr = (r & 3) + 8 * (r >> 2) + 4 * hl;
        ins3(sa0, sa1, sa2, pk(acc[ct][0][r], w * 64 + rowr));
        ins3(sb0, sb1, sb2, pk(acc[ct][1][r], w * 64 + 32 + rowr));
      }
      mrg3(sa0, sa1, sa2, sb0, sb1, sb2);
      // lanes l and l^32 hold disjoint row-halves of the same item: one butterfly
      {
        float b0k = __shfl_xor(sa0, 32), b1k = __shfl_xor(sa1, 32), b2k = __shfl_xor(sa2, 32);
        mrg3(sa0, sa1, sa2, b0k, b1k, b2k);
      }
      if (lane < 32) {
        float4 v; v.x = sa0; v.y = sa1; v.z = sa2; v.w = FMAXV;
        *(float4*)&keybuf[ct * 32 + lane][w][0] = v;
      }
    }
    __syncthreads();   // barrier 2: keybuf ready (also: all Rh reads done)

    // ---- cross-wave merge in the owner quad ----
    int jm;
    {
      float4 v = *(const float4*)&keybuf[it_o][kq][0];
      float s0 = v.x, s1 = v.y, s2 = v.z;
      {
        float b0k = __shfl_xor(s0, 1), b1k = __shfl_xor(s1, 1), b2k = __shfl_xor(s2, 1);
        mrg3(s0, s1, s2, b0k, b1k, b2k);
        b0k = __shfl_xor(s0, 2); b1k = __shfl_xor(s1, 2); b2k = __shfl_xor(s2, 2);
        mrg3(s0, s1, s2, b0k, b1k, b2k);
      }
      jm = (int)(__float_as_uint(s0) & 255u);
      const float gap = unpv(s1) - unpv(s0);   // d/2 scale
      if (gap < TAUH) {   // quad-uniform: exact fp32 rescore of top-3
        const int cand[3] = { jm, (int)(__float_as_uint(s1) & 255u),
                                  (int)(__float_as_uint(s2) & 255u) };
        float bestd = FMAXV; int bestj = 0;
#pragma unroll 1
        for (int cc = 0; cc < 3; ++cc) {
          const int j = cand[cc];
          const float* row = cbf32 + (size_t)j * ED + kq * 64;
          float p2 = 0.f;
#pragma unroll
          for (int i = 0; i < 16; ++i) {
            float4 q = *(const float4*)(row + 4 * i);
            p2 = fmaf(res[4 * i + 0], q.x, p2);
            p2 = fmaf(res[4 * i + 1], q.y, p2);
            p2 = fmaf(res[4 * i + 2], q.z, p2);
            p2 = fmaf(res[4 * i + 3], q.w, p2);
          }
          p2 += __shfl_xor(p2, 1);
          p2 += __shfl_xor(p2, 2);
          const float d = fmaf(-2.f, p2, nrm[j]);
          if (d < bestd || (d == bestd && j < bestj)) { bestd = d; bestj = j; }
        }
        jm = bestj;
      }
      if (kq == 0) {
        const size_t ioff = (br ? OFF_RIDX : OFF_SIDX) + (size_t)(b0 + it_o) * NQL + lev;
        out[ioff] = (float)jm;
      }
    }

    // ---- residual update + loss (exact reference rounding chain) ----
    {
      const float* crow = cbf32 + (size_t)jm * ED + kq * 64;
#pragma unroll
      for (int i = 0; i < 16; ++i) {
        float4 q = *(const float4*)(crow + 4 * i);
#pragma unroll
        for (int u = 0; u < 4; ++u) {
          float cv = (u == 0 ? q.x : u == 1 ? q.y : u == 2 ? q.z : q.w);
          float r  = res[4 * i + u];
          float dd = cv - r;
          if (u & 1) lossB = fmaf(dd, dd, lossB);   // 2 chains: break serial dep
          else       lossA = fmaf(dd, dd, lossA);
          float xr = r + dd;      // straight-through x_res
          res[4 * i + u] = r - xr;
        }
      }
    }
  }

  // ---- x_q = x - res_final ----
  {
    const float* xp = x + (size_t)(b0 + it_o) * (2 * ED) + br * ED + kq * 64;
    float* op = out + (br ? OFF_REC : 0) + (size_t)(b0 + it_o) * ED + kq * 64;
#pragma unroll
    for (int i = 0; i < 16; ++i) {
      float4 xv = *(const float4*)(xp + 4 * i);
      float4 o;
      o.x = xv.x - res[4 * i + 0];
      o.y = xv.y - res[4 * i + 1];
      o.z = xv.z - res[4 * i + 2];
      o.w = xv.w - res[4 * i + 3];
      *(float4*)(op + 4 * i) = o;
    }
  }

  // ---- loss: one wave-reduce + one atomic per block (8 slots) ----
  float lossReg = lossA + lossB;
#pragma unroll
  for (int d = 1; d < 64; d <<= 1) lossReg += __shfl_xor(lossReg, d);
  if (lane == 0) redS[w] = lossReg;
  __syncthreads();
  if (tid == 0)
    atomicAdd(&lossAcc[blockIdx.x & 7], (double)((redS[0] + redS[1]) + (redS[2] + redS[3])));
}

// ---- finalize scalar loss ----
__global__ void kFin(const double* __restrict__ lossAcc, float* __restrict__ out) {
  if (blockIdx.x == 0 && threadIdx.x == 0) {
    double s = 0.0;
    for (int l = 0; l < 8; ++l) s += lossAcc[l];
    out[OFF_LOSS] = (float)(s * 1.25 / ((double)NB * ED) / 8.0);
  }
}

extern "C" void kernel_launch(void* const* d_in, const int* in_sizes, int n_in,
                              void* d_out, int out_size, void* d_ws, size_t ws_size,
                              hipStream_t stream) {
  const float* x   = (const float*)d_in[0];
  const float* cbS = (const float*)d_in[1];
  const float* cbR = (const float*)d_in[2];
  float* out = (float*)d_out;
  char*  ws  = (char*)d_ws;

  double* lossAcc = (double*)(ws + WS_LOSS);
  float*  norms   = (float*)(ws + WS_NORM);
  f16*    cbH     = (f16*)(ws + WS_CBH);

  hipLaunchKernelGGL(kPrep,  dim3(8),    dim3(256), 0, stream, cbS, cbR, norms, lossAcc);
  hipLaunchKernelGGL(kConvH, dim3(2048), dim3(256), 0, stream, cbS, cbR, cbH);
  hipLaunchKernelGGL(kMain,  dim3(NB / 64, 2), dim3(256), 0, stream,
                     x, cbS, cbR, cbH, norms, lossAcc, out);
  hipLaunchKernelGGL(kFin,   dim3(1),    dim3(64),  0, stream, lossAcc, out);
}

// Round 21
// 558.446 us; speedup vs baseline: 1.0343x; 1.0343x over previous
//
#include <hip/hip_runtime.h>
#include <hip/hip_bf16.h>
#include <hip/hip_fp16.h>
#include <cstdint>
#include <cstddef>

#define NB   131072   // items
#define ED   256      // e_dim
#define NQL  4        // levels
#define NEC  256      // codebook entries

typedef _Float16 f16;
typedef f16  f16x8 __attribute__((ext_vector_type(8)));
typedef float f32x4 __attribute__((ext_vector_type(4)));

static constexpr float FMAXV = 3.402823466e+38f;
static constexpr float TAUH  = 0.078125f;   // rescore gate, d/2 units

static constexpr size_t OFF_REC  = (size_t)NB * ED;
static constexpr size_t OFF_LOSS = 2 * (size_t)NB * ED;
static constexpr size_t OFF_SIDX = OFF_LOSS + 1;
static constexpr size_t OFF_RIDX = OFF_SIDX + (size_t)NB * NQL;

// workspace layout (bytes)
static constexpr size_t WS_LOSS = 0;                      // 8 doubles
static constexpr size_t WS_NORM = 256;                    // 8*256 f32 (norm - 256)
static constexpr size_t WS_CBH  = 256 + 8 * 256 * 4;      // 8448; 8*256*256 f16 (1 MB)

// ---- prep: zero loss accumulators + codebook row norms (pre-shifted by -256) ----
__global__ void kPrep(const float* __restrict__ cbS, const float* __restrict__ cbR,
                      float* __restrict__ norms, double* __restrict__ lossAcc) {
  const int cbi = blockIdx.x;    // 0..7
  const int j   = threadIdx.x;   // 0..255
  if (cbi == 0 && j < 8) lossAcc[j] = 0.0;
  const float* row = (cbi < 4 ? cbS : cbR) + ((size_t)(cbi & 3) * NEC + j) * ED;
  float acc = 0.f;
  for (int k = 0; k < ED; k += 4) {
    float4 v = *(const float4*)(row + k);
    acc += v.x * v.x + v.y * v.y + v.z * v.z + v.w * v.w;
  }
  norms[cbi * NEC + j] = acc - 256.0f;   // exact shift (Sterbenz range)
}

// ---- NEGATED f16 copy of codebooks: acc = 0.5*nrm + sum(-c)*r = d/2 ----
__global__ void kConvH(const float* __restrict__ cbS, const float* __restrict__ cbR,
                       f16* __restrict__ cbH) {
  const int f   = blockIdx.x * 256 + threadIdx.x;   // 0..524287
  const int cbi = f >> 16;
  const int rem = f & 65535;
  const float v = (cbi < 4 ? cbS + ((size_t)cbi << 16) : cbR + ((size_t)(cbi - 4) << 16))[rem];
  cbH[f] = (f16)(-v);   // RTN, negated
}

// packed key helpers: low 8 mantissa bits carry the codeword index
__device__ __forceinline__ float pk(float v, int j) {
  return __uint_as_float((__float_as_uint(v) & ~255u) | (unsigned)j);
}
__device__ __forceinline__ float unpv(float k) {
  return __uint_as_float(__float_as_uint(k) & ~255u);
}
__device__ __forceinline__ void ins3(float& s0, float& s1, float& s2, float k) {
  float t0 = fmaxf(s0, k); s0 = fminf(s0, k);
  float t1 = fmaxf(s1, t0); s1 = fminf(s1, t0);
  s2 = fminf(s2, t1);
}
__device__ __forceinline__ void mrg3(float& a0, float& a1, float& a2,
                                     float b0, float b1, float b2) {
  float x  = fmaxf(a0, b0);
  float c0 = fminf(a0, b0);
  float m1 = fminf(a1, b1), M1 = fmaxf(a1, b1);
  float c1 = fminf(fminf(x, a1), b1);
  float c2 = fminf(fminf(fmaxf(x, m1), M1), fminf(a2, b2));
  a0 = c0; a1 = c1; a2 = c2;
}

// ---- main fused RVQ kernel: the measured optimum of this family (r13/r19) ----
// 64 items/block, 4 waves, acc[4][4] — inner batch 8 loads : 16 MFMA (density
// law: 12:16 r14, 8:8 r9, 5:4 r12 all regressed). Registers: res[64] + 4 frag
// buffers = 128 = exact arch-VGPR fit at bounds(256,2) (half-split rule;
// deeper prefetch spills — r16/r17; 16x16 beats 32x32 shape at this occupancy
// — r20). Branch-split grid, d/2 trick (0.5*nrm acc init + negated f16
// codebook), 2-deep ping-pong, setprio on MFMA clusters, 2 barriers/level,
// packed-key top-3 + TAUH-gated exact fp32 rescore (argmin == reference).
__global__ __launch_bounds__(256, 2)
void kMain(const float* __restrict__ x,
           const float* __restrict__ cbS,
           const float* __restrict__ cbR,
           const f16*  __restrict__ cbH,
           const float* __restrict__ norms,
           double* __restrict__ lossAcc,
           float* __restrict__ out) {
  __shared__ __align__(16) char  RhBuf[64 * 512];      // f16 residual image (32 KB)
  __shared__ __align__(16) float keybuf[64][4][4];     // per-wave top-3 per item (4 KB)
  __shared__ float redS[4];

  const int tid   = threadIdx.x;
  const int lane  = tid & 63;
  const int w     = tid >> 6;       // wave: owns codewords [64w, 64w+64)
  const int it_o  = tid >> 2;       // owner item 0..63
  const int kq    = tid & 3;        // owner k-quarter
  const int b0    = blockIdx.x * 64;
  const int br    = blockIdx.y;     // branch (src/rec) — one 4-level chain/block
  const int l15   = lane & 15;
  const int l4    = lane >> 4;

  const float* cbf32base = br ? cbR : cbS;
  float res[64];
  float lossA = 0.f, lossB = 0.f;

  // ---- load residual = x[:, br*E .. br*E+E) slice into registers ----
  {
    const float* xp = x + (size_t)(b0 + it_o) * (2 * ED) + br * ED + kq * 64;
#pragma unroll
    for (int i = 0; i < 16; ++i) {
      float4 v = *(const float4*)(xp + 4 * i);
      res[4 * i + 0] = v.x; res[4 * i + 1] = v.y;
      res[4 * i + 2] = v.z; res[4 * i + 3] = v.w;
    }
  }

#pragma unroll 1
  for (int lev = 0; lev < NQL; ++lev) {
    const int cbi = br * 4 + lev;
    const float* nrm = norms + (size_t)cbi * NEC;
    const f16*   cbh = cbH + ((size_t)cbi << 16);
    const float* cbf32 = cbf32base + (size_t)lev * NEC * ED;

    // ---- stage res -> Rh (f16, RTN), swizzled rows of 512B ----
#pragma unroll
    for (int c = 0; c < 8; ++c) {
      f16x8 h;
#pragma unroll
      for (int u = 0; u < 8; ++u) h[u] = (f16)res[c * 8 + u];
      int off = it_o * 512 + kq * 128 + c * 16;
      off ^= (it_o & 7) << 4;
      *(f16x8*)&RhBuf[off] = h;
    }
    __syncthreads();   // barrier 1: Rh ready

    // ---- acc init = 0.5*nrm -> acc_final = d/2 (negated cbH) ----
    f32x4 acc[4][4];
#pragma unroll
    for (int nt = 0; nt < 4; ++nt) {
      float4 nv = *(const float4*)&nrm[w * 64 + nt * 16 + l4 * 4];
      f32x4 h; h[0] = 0.5f * nv.x; h[1] = 0.5f * nv.y;
      h[2] = 0.5f * nv.z; h[3] = 0.5f * nv.w;
#pragma unroll
      for (int mt = 0; mt < 4; ++mt) acc[mt][nt] = h;
    }

    // ---- GEMM: 64x64 tile/wave, 2-deep ping-pong pipeline ----
    f16x8 A0[4], B0[4], A1[4], B1[4];
#define LOADA(Adst, ks_)                                                        \
    {                                                                           \
      _Pragma("unroll")                                                         \
      for (int mt = 0; mt < 4; ++mt) {                                          \
        const int it = mt * 16 + l15;                                           \
        const int offA = (it * 512 + (ks_) * 64 + l4 * 16) ^ ((it & 7) << 4);   \
        Adst[mt] = *(const f16x8*)&RhBuf[offA];                                 \
      }                                                                         \
    }
#define LOADB(Bdst, ks_)                                                        \
    {                                                                           \
      _Pragma("unroll")                                                         \
      for (int nt = 0; nt < 4; ++nt) {                                          \
        const int j = w * 64 + nt * 16 + l15;                                   \
        Bdst[nt] = *(const f16x8*)&cbh[(size_t)j * ED + (ks_) * 32 + l4 * 8];   \
      }                                                                         \
    }
#define MFMA16(Aop, Bop)                                                        \
    {                                                                           \
      __builtin_amdgcn_s_setprio(1);                                            \
      _Pragma("unroll")                                                         \
      for (int mt = 0; mt < 4; ++mt)                                            \
        _Pragma("unroll")                                                       \
        for (int nt = 0; nt < 4; ++nt)                                          \
          acc[mt][nt] = __builtin_amdgcn_mfma_f32_16x16x32_f16(                 \
              Bop[nt], Aop[mt], acc[mt][nt], 0, 0, 0);                          \
      __builtin_amdgcn_s_setprio(0);                                            \
    }

    LOADA(A0, 0); LOADB(B0, 0);
#pragma unroll 1
    for (int ks2 = 0; ks2 < 4; ++ks2) {
      LOADA(A1, 2 * ks2 + 1); LOADB(B1, 2 * ks2 + 1);   // issue next batch first
      MFMA16(A0, B0);
      if (ks2 < 3) { LOADA(A0, 2 * ks2 + 2); LOADB(B0, 2 * ks2 + 2); }
      MFMA16(A1, B1);
    }
#undef LOADA
#undef LOADB
#undef MFMA16

    // ---- argmin: lane holds 16 j-keys (nt x r) for item = mt*16+l15 ----
#pragma unroll
    for (int mt = 0; mt < 4; ++mt) {
      float s0 = FMAXV, s1 = FMAXV, s2 = FMAXV;
#pragma unroll
      for (int nt = 0; nt < 4; ++nt)
#pragma unroll
        for (int r = 0; r < 4; ++r)
          ins3(s0, s1, s2, pk(acc[mt][nt][r], w * 64 + nt * 16 + l4 * 4 + r));
      // merge the 4 l4-groups (disjoint j-subsets, same item): xor 16, 32
      {
        float b0k = __shfl_xor(s0, 16), b1k = __shfl_xor(s1, 16), b2k = __shfl_xor(s2, 16);
        mrg3(s0, s1, s2, b0k, b1k, b2k);
        b0k = __shfl_xor(s0, 32); b1k = __shfl_xor(s1, 32); b2k = __shfl_xor(s2, 32);
        mrg3(s0, s1, s2, b0k, b1k, b2k);
      }
      if (l4 == 0) {   // lanes 0..15 write item mt*16+l15
        float4 v; v.x = s0; v.y = s1; v.z = s2; v.w = FMAXV;
        *(float4*)&keybuf[mt * 16 + l15][w][0] = v;
      }
    }
    __syncthreads();   // barrier 2: keybuf ready (also: all Rh reads done)

    // ---- cross-wave merge in the owner quad ----
    int jm;
    {
      float4 v = *(const float4*)&keybuf[it_o][kq][0];
      float s0 = v.x, s1 = v.y, s2 = v.z;
      {
        float b0k = __shfl_xor(s0, 1), b1k = __shfl_xor(s1, 1), b2k = __shfl_xor(s2, 1);
        mrg3(s0, s1, s2, b0k, b1k, b2k);
        b0k = __shfl_xor(s0, 2); b1k = __shfl_xor(s1, 2); b2k = __shfl_xor(s2, 2);
        mrg3(s0, s1, s2, b0k, b1k, b2k);
      }
      jm = (int)(__float_as_uint(s0) & 255u);
      const float gap = unpv(s1) - unpv(s0);   // d/2 scale
      if (gap < TAUH) {   // quad-uniform: exact fp32 rescore of top-3
        const int cand[3] = { jm, (int)(__float_as_uint(s1) & 255u),
                                  (int)(__float_as_uint(s2) & 255u) };
        float bestd = FMAXV; int bestj = 0;
#pragma unroll 1
        for (int cc = 0; cc < 3; ++cc) {
          const int j = cand[cc];
          const float* row = cbf32 + (size_t)j * ED + kq * 64;
          float p2 = 0.f;
#pragma unroll
          for (int i = 0; i < 16; ++i) {
            float4 q = *(const float4*)(row + 4 * i);
            p2 = fmaf(res[4 * i + 0], q.x, p2);
            p2 = fmaf(res[4 * i + 1], q.y, p2);
            p2 = fmaf(res[4 * i + 2], q.z, p2);
            p2 = fmaf(res[4 * i + 3], q.w, p2);
          }
          p2 += __shfl_xor(p2, 1);
          p2 += __shfl_xor(p2, 2);
          const float d = fmaf(-2.f, p2, nrm[j]);
          if (d < bestd || (d == bestd && j < bestj)) { bestd = d; bestj = j; }
        }
        jm = bestj;
      }
      if (kq == 0) {
        const size_t ioff = (br ? OFF_RIDX : OFF_SIDX) + (size_t)(b0 + it_o) * NQL + lev;
        out[ioff] = (float)jm;
      }
    }

    // ---- residual update + loss (exact reference rounding chain) ----
    {
      const float* crow = cbf32 + (size_t)jm * ED + kq * 64;
#pragma unroll
      for (int i = 0; i < 16; ++i) {
        float4 q = *(const float4*)(crow + 4 * i);
#pragma unroll
        for (int u = 0; u < 4; ++u) {
          float cv = (u == 0 ? q.x : u == 1 ? q.y : u == 2 ? q.z : q.w);
          float r  = res[4 * i + u];
          float dd = cv - r;
          if (u & 1) lossB = fmaf(dd, dd, lossB);   // 2 chains: break serial dep
          else       lossA = fmaf(dd, dd, lossA);
          float xr = r + dd;      // straight-through x_res
          res[4 * i + u] = r - xr;
        }
      }
    }
  }

  // ---- x_q = x - res_final ----
  {
    const float* xp = x + (size_t)(b0 + it_o) * (2 * ED) + br * ED + kq * 64;
    float* op = out + (br ? OFF_REC : 0) + (size_t)(b0 + it_o) * ED + kq * 64;
#pragma unroll
    for (int i = 0; i < 16; ++i) {
      float4 xv = *(const float4*)(xp + 4 * i);
      float4 o;
      o.x = xv.x - res[4 * i + 0];
      o.y = xv.y - res[4 * i + 1];
      o.z = xv.z - res[4 * i + 2];
      o.w = xv.w - res[4 * i + 3];
      *(float4*)(op + 4 * i) = o;
    }
  }

  // ---- loss: one wave-reduce + one atomic per block (8 slots) ----
  float lossReg = lossA + lossB;
#pragma unroll
  for (int d = 1; d < 64; d <<= 1) lossReg += __shfl_xor(lossReg, d);
  if (lane == 0) redS[w] = lossReg;
  __syncthreads();
  if (tid == 0)
    atomicAdd(&lossAcc[blockIdx.x & 7], (double)((redS[0] + redS[1]) + (redS[2] + redS[3])));
}

// ---- finalize scalar loss ----
__global__ void kFin(const double* __restrict__ lossAcc, float* __restrict__ out) {
  if (blockIdx.x == 0 && threadIdx.x == 0) {
    double s = 0.0;
    for (int l = 0; l < 8; ++l) s += lossAcc[l];
    out[OFF_LOSS] = (float)(s * 1.25 / ((double)NB * ED) / 8.0);
  }
}

extern "C" void kernel_launch(void* const* d_in, const int* in_sizes, int n_in,
                              void* d_out, int out_size, void* d_ws, size_t ws_size,
                              hipStream_t stream) {
  const float* x   = (const float*)d_in[0];
  const float* cbS = (const float*)d_in[1];
  const float* cbR = (const float*)d_in[2];
  float* out = (float*)d_out;
  char*  ws  = (char*)d_ws;

  double* lossAcc = (double*)(ws + WS_LOSS);
  float*  norms   = (float*)(ws + WS_NORM);
  f16*    cbH     = (f16*)(ws + WS_CBH);

  hipLaunchKernelGGL(kPrep,  dim3(8),    dim3(256), 0, stream, cbS, cbR, norms, lossAcc);
  hipLaunchKernelGGL(kConvH, dim3(2048), dim3(256), 0, stream, cbS, cbR, cbH);
  hipLaunchKernelGGL(kMain,  dim3(NB / 64, 2), dim3(256), 0, stream,
                     x, cbS, cbR, cbH, norms, lossAcc, out);
  hipLaunchKernelGGL(kFin,   dim3(1),    dim3(64),  0, stream, lossAcc, out);
}